// Round 2
// baseline (167.211 us; speedup 1.0000x reference)
//
#include <hip/hip_runtime.h>
#include <hip/hip_bf16.h>

// NoSharedRnnAgent: per-agent fc1+ReLU -> GRU cell -> fc2, 32 agents, B=256.
// Round 2: fused GRU kernel (gx+gh+gates in one dispatch, K=1024 concat GEMM),
// 64x64 tiles for 4-5 resident blocks/CU (latency hiding), XCD-chunked swizzle.
//
// d_in: 0=inputs[8192,512] 1=hidden[8192,512] 2=W1[32,512,512] 3=b1[32,512]
//       4=W_ih[32,1536,512] 5=b_ih[32,1536] 6=W_hh[32,1536,512] 7=b_hh[32,1536]
//       8=W2[32,64,512] 9=b2[32,64]
// d_out: q[8192,64] fp32, then h[8192,512] fp32. Global row = b*32 + a.

typedef __attribute__((ext_vector_type(8))) __bf16 bf16x8;
typedef __attribute__((ext_vector_type(4))) float  f32x4;

constexpr int NAGENT = 32;
constexpr int KC     = 512;   // per-matrix K
constexpr int MROWS  = 256;   // batch rows per agent

__device__ __forceinline__ bf16x8 cvt8(const float* p) {
  f32x4 u = *(const f32x4*)p;
  f32x4 v = *(const f32x4*)(p + 4);
  bf16x8 w;
  w[0] = (__bf16)u[0]; w[1] = (__bf16)u[1]; w[2] = (__bf16)u[2]; w[3] = (__bf16)u[3];
  w[4] = (__bf16)v[0]; w[5] = (__bf16)v[1]; w[6] = (__bf16)v[2]; w[7] = (__bf16)v[3];
  return w;
}
__device__ __forceinline__ float sigmoid_f(float x) { return 1.f / (1.f + __expf(-x)); }
__device__ __forceinline__ float tanh_f(float x) {
  float xc = fminf(fmaxf(x, -15.f), 15.f);
  float a = __expf(2.f * xc);
  return (a - 1.f) / (a + 1.f);
}

// Bijective XCD-chunk swizzle (grid % 8 == 0): adjacent wg land on same XCD.
__device__ __forceinline__ int xcd_swz(int bid, int nwg) {
  return (bid & 7) * (nwg >> 3) + (bid >> 3);
}

// C[M,N] = act(A[M,K=512] @ W[N,K]^T + bias), per agent. 64x64 tile, 4 waves.
// A row r at Ap[((b0+r)*32 + a)*512 + k]; W row n at Wp[(a*N + n)*512 + k] (fp32).
// LDS [buf][kslice][row][8 bf16]: conflict-balanced for b128 write+read.
template <bool ABF16, int ACT, bool OBF16>
__global__ __launch_bounds__(256) void gemm64(
    const void* __restrict__ Ap, const float* __restrict__ Wp,
    const float* __restrict__ bp, void* __restrict__ Op, const int N) {
  constexpr int BM = 64, BN = 64, MT = MROWS / BM;  // MT=4, M-fastest in wg
  const int NT = N >> 6;
  const int wg = xcd_swz(blockIdx.x, gridDim.x);
  const int a  = wg / (MT * NT);
  const int rem = wg % (MT * NT);
  const int n0 = (rem / MT) * BN;
  const int b0 = (rem % MT) * BM;

  __shared__ __attribute__((aligned(16))) __bf16 lA[2][4][BM][8];
  __shared__ __attribute__((aligned(16))) __bf16 lB[2][4][BN][8];

  const int tid = threadIdx.x;
  const int lane = tid & 63;
  const int wn = tid >> 6;          // 4 waves, each owns 16 output cols
  const int lr = lane & 15, lk = lane >> 4;

  const int ar = tid >> 2, aks = tid & 3;  // one 8-elem chunk per thread (A and B)
  const size_t aoff = ((size_t)(b0 + ar) * NAGENT + a) * KC + aks * 8;
  const size_t boff = ((size_t)a * N + n0 + ar) * KC + aks * 8;

  const float*  Af = (const float*)Ap;
  const __bf16* Ab = (const __bf16*)Ap;

  bf16x8 sA, sB;
  auto loadT = [&](int t) {
    if constexpr (ABF16) sA = *(const bf16x8*)(Ab + aoff + t * 32);
    else                 sA = cvt8(Af + aoff + t * 32);
    sB = cvt8(Wp + boff + t * 32);
  };
  auto writeT = [&](int buf) {
    *(bf16x8*)(&lA[buf][aks][ar][0]) = sA;
    *(bf16x8*)(&lB[buf][aks][ar][0]) = sB;
  };

  f32x4 acc[4] = {};
  auto computeT = [&](int buf) {
    bf16x8 bv = *(const bf16x8*)(&lB[buf][lk][wn * 16 + lr][0]);
#pragma unroll
    for (int i = 0; i < 4; ++i) {
      bf16x8 af = *(const bf16x8*)(&lA[buf][lk][i * 16 + lr][0]);
      acc[i] = __builtin_amdgcn_mfma_f32_16x16x32_bf16(af, bv, acc[i], 0, 0, 0);
    }
  };

  loadT(0); writeT(0);
  int cur = 0;
#pragma unroll 1
  for (int t = 0; t < KC / 32; ++t) {
    __syncthreads();
    if (t + 1 < KC / 32) loadT(t + 1);
    computeT(cur);
    if (t + 1 < KC / 32) { writeT(cur ^ 1); cur ^= 1; }
  }

  // epilogue (C/D map: col=lane&15, row=(lane>>4)*4+e)
  const int col = n0 + wn * 16 + lr;
  const float bias = bp[(size_t)a * N + col];
#pragma unroll
  for (int i = 0; i < 4; ++i) {
    const int r0 = b0 + i * 16 + lk * 4;
#pragma unroll
    for (int e = 0; e < 4; ++e) {
      float v = acc[i][e] + bias;
      if (ACT == 1) v = fmaxf(v, 0.f);
      const size_t o = ((size_t)(r0 + e) * NAGENT + a) * N + col;
      if constexpr (OBF16) ((__bf16*)Op)[o] = (__bf16)v;
      else                 ((float*)Op)[o]  = v;
    }
  }
}

// Fused GRU: for a 64-row x 64-col tile, accumulate over K=1024 concat
// [x1 | hidden] x [W_ih | W_hh] for gates r,z (fused) and n (split: xn from
// W_ih phase, hn from W_hh phase), then apply gate math and write h.
__global__ __launch_bounds__(256) void gru_fused(
    const __bf16* __restrict__ x1, const float* __restrict__ hidden,
    const float* __restrict__ Wih, const float* __restrict__ bih,
    const float* __restrict__ Whh, const float* __restrict__ bhh,
    float* __restrict__ hout, __bf16* __restrict__ hbf) {
  constexpr int BM = 64, BN = 64, MT = 4, NT = 8;  // NT = 512/64
  const int wg = xcd_swz(blockIdx.x, gridDim.x);
  const int a  = wg / (MT * NT);
  const int rem = wg % (MT * NT);
  const int n0 = (rem / MT) * BN;
  const int b0 = (rem % MT) * BM;

  __shared__ __attribute__((aligned(16))) __bf16 lA[2][4][BM][8];
  __shared__ __attribute__((aligned(16))) __bf16 lB[2][4][3 * BN][8];  // r|z|n rows

  const int tid = threadIdx.x;
  const int lane = tid & 63;
  const int wn = tid >> 6;
  const int lr = lane & 15, lk = lane >> 4;

  const int ar = tid >> 2, aks = tid & 3;
  const size_t aoff = ((size_t)(b0 + ar) * NAGENT + a) * KC + aks * 8;
  // B chunk c covers gate c, row ar (since (tid + c*256)>>2 == ar + c*64)
  size_t woff[3];
#pragma unroll
  for (int c = 0; c < 3; ++c)
    woff[c] = ((size_t)a * 1536 + c * 512 + n0 + ar) * KC + aks * 8;

  bf16x8 sA, sB[3];
  auto loadT = [&](int t) {
    if (t < 16) {
      sA = *(const bf16x8*)(x1 + aoff + t * 32);
#pragma unroll
      for (int c = 0; c < 3; ++c) sB[c] = cvt8(Wih + woff[c] + t * 32);
    } else {
      sA = cvt8(hidden + aoff + (t - 16) * 32);
#pragma unroll
      for (int c = 0; c < 3; ++c) sB[c] = cvt8(Whh + woff[c] + (t - 16) * 32);
    }
  };
  auto writeT = [&](int buf) {
    *(bf16x8*)(&lA[buf][aks][ar][0]) = sA;
#pragma unroll
    for (int c = 0; c < 3; ++c)
      *(bf16x8*)(&lB[buf][aks][c * 64 + ar][0]) = sB[c];
  };

  f32x4 accR[4] = {}, accZ[4] = {}, accXN[4] = {}, accHN[4] = {};
  auto computeT = [&](int buf, f32x4 (&accN)[4]) {
    bf16x8 bvR = *(const bf16x8*)(&lB[buf][lk][0 * 64 + wn * 16 + lr][0]);
    bf16x8 bvZ = *(const bf16x8*)(&lB[buf][lk][1 * 64 + wn * 16 + lr][0]);
    bf16x8 bvN = *(const bf16x8*)(&lB[buf][lk][2 * 64 + wn * 16 + lr][0]);
#pragma unroll
    for (int i = 0; i < 4; ++i) {
      bf16x8 af = *(const bf16x8*)(&lA[buf][lk][i * 16 + lr][0]);
      accR[i] = __builtin_amdgcn_mfma_f32_16x16x32_bf16(af, bvR, accR[i], 0, 0, 0);
      accZ[i] = __builtin_amdgcn_mfma_f32_16x16x32_bf16(af, bvZ, accZ[i], 0, 0, 0);
      accN[i] = __builtin_amdgcn_mfma_f32_16x16x32_bf16(af, bvN, accN[i], 0, 0, 0);
    }
  };

  loadT(0); writeT(0);
  int cur = 0;
  // phase 0: K from x1 @ W_ih (t = 0..15); n-gate -> accXN
#pragma unroll 1
  for (int t = 0; t < 16; ++t) {
    __syncthreads();
    loadT(t + 1);  // t=15 loads t=16 -> hidden/Whh path
    computeT(cur, accXN);
    writeT(cur ^ 1); cur ^= 1;
  }
  // phase 1: K from hidden @ W_hh (t = 16..31); n-gate -> accHN
#pragma unroll 1
  for (int t = 16; t < 32; ++t) {
    __syncthreads();
    if (t + 1 < 32) loadT(t + 1);
    computeT(cur, accHN);
    if (t + 1 < 32) { writeT(cur ^ 1); cur ^= 1; }
  }

  // epilogue: GRU gate math fully in-register (each thread owns r,z,xn,hn
  // for the same (row, col) set), h_in re-read fp32 (L2-hot from K-loop).
  const int col = n0 + wn * 16 + lr;
  const size_t ab = (size_t)a * 1536 + col;
  const float br_ = bih[ab] + bhh[ab];
  const float bz_ = bih[ab + 512] + bhh[ab + 512];
  const float bxn = bih[ab + 1024];
  const float bhn = bhh[ab + 1024];
#pragma unroll
  for (int i = 0; i < 4; ++i) {
    const int r0 = b0 + i * 16 + lk * 4;
#pragma unroll
    for (int e = 0; e < 4; ++e) {
      const size_t o = ((size_t)(r0 + e) * NAGENT + a) * KC + col;
      const float hprev = hidden[o];
      const float r = sigmoid_f(accR[i][e] + br_);
      const float z = sigmoid_f(accZ[i][e] + bz_);
      const float n = tanh_f((accXN[i][e] + bxn) + r * (accHN[i][e] + bhn));
      const float h = (1.f - z) * n + z * hprev;
      hout[o] = h;
      hbf[o] = (__bf16)h;
    }
  }
}

extern "C" void kernel_launch(void* const* d_in, const int* in_sizes, int n_in,
                              void* d_out, int out_size, void* d_ws, size_t ws_size,
                              hipStream_t stream) {
  const float* inputs = (const float*)d_in[0];
  const float* hidden = (const float*)d_in[1];
  const float* W1   = (const float*)d_in[2];
  const float* b1   = (const float*)d_in[3];
  const float* W_ih = (const float*)d_in[4];
  const float* b_ih = (const float*)d_in[5];
  const float* W_hh = (const float*)d_in[6];
  const float* b_hh = (const float*)d_in[7];
  const float* W2   = (const float*)d_in[8];
  const float* b2   = (const float*)d_in[9];

  float* out_q = (float*)d_out;
  float* out_h = out_q + (size_t)8192 * 64;

  char* ws = (char*)d_ws;
  __bf16* x1  = (__bf16*)(ws);                      // 8 MiB [8192,512] bf16
  __bf16* hbf = (__bf16*)(ws + ((size_t)8 << 20));  // 8 MiB [8192,512] bf16

  // fc1: x1 = relu(inputs @ W1^T + b1)   grid = 32 agents * 4 M * 8 N
  gemm64<false, 1, true><<<32 * 4 * 8, 256, 0, stream>>>(inputs, W1, b1, x1, 512);
  // fused GRU: h = gru(x1, hidden)       grid = 32 * 4 M * 8 N
  gru_fused<<<32 * 4 * 8, 256, 0, stream>>>(x1, hidden, W_ih, b_ih, W_hh, b_hh,
                                            out_h, hbf);
  // fc2: q = h @ W2^T + b2               grid = 32 * 4 M * 1 N
  gemm64<true, 0, false><<<32 * 4 * 1, 256, 0, stream>>>(hbf, W2, b2, out_q, 64);
}

// Round 3
// 100.567 us; speedup vs baseline: 1.6627x; 1.6627x over previous
//
#include <hip/hip_runtime.h>
#include <hip/hip_bf16.h>

// NoSharedRnnAgent: per-agent fc1+ReLU -> GRU cell -> fc2, 32 agents, B=256.
// Round 3: traffic-minimal tiling. Model validated on rounds 1-2:
//   time ~= total read traffic / ~7 TB/s (HBM+L3 combined delivery).
// BM=256 (W read exactly once), BN=192 (3 gates x 64 cols, gate math fused in
// epilogue), grid=256 (1 block/CU), XOR-swizzled LDS (conflict-free b128 r/w),
// XCD swizzle so same-agent blocks share A via their XCD's L2.
//
// d_in: 0=inputs[8192,512] 1=hidden[8192,512] 2=W1[32,512,512] 3=b1[32,512]
//       4=W_ih[32,1536,512] 5=b_ih[32,1536] 6=W_hh[32,1536,512] 7=b_hh[32,1536]
//       8=W2[32,64,512] 9=b2[32,64]
// d_out: q[8192,64] fp32, then h[8192,512] fp32. Global row = b*32 + a.

typedef __attribute__((ext_vector_type(8))) __bf16 bf16x8;
typedef __attribute__((ext_vector_type(4))) float  f32x4;

constexpr int NAGENT = 32;
constexpr int KC     = 512;

__device__ __forceinline__ bf16x8 cvt8(const float* p) {
  f32x4 u = *(const f32x4*)p;
  f32x4 v = *(const f32x4*)(p + 4);
  bf16x8 w;
  w[0] = (__bf16)u[0]; w[1] = (__bf16)u[1]; w[2] = (__bf16)u[2]; w[3] = (__bf16)u[3];
  w[4] = (__bf16)v[0]; w[5] = (__bf16)v[1]; w[6] = (__bf16)v[2]; w[7] = (__bf16)v[3];
  return w;
}
__device__ __forceinline__ float sigmoid_f(float x) { return 1.f / (1.f + __expf(-x)); }
__device__ __forceinline__ float tanh_f(float x) {
  float xc = fminf(fmaxf(x, -15.f), 15.f);
  float a = __expf(2.f * xc);
  return (a - 1.f) / (a + 1.f);
}
// Bijective XCD-chunk swizzle (grid % 8 == 0).
__device__ __forceinline__ int xcd_swz(int bid, int nwg) {
  return (bid & 7) * (nwg >> 3) + (bid >> 3);
}

// ---------------------------------------------------------------------------
// fc1: x1 = relu(inputs @ W1^T + b1). BM=256 (all rows of one agent), BN=64.
// Grid 256 = 32 agents x 8 N-tiles. 512 threads (8 waves: wm=wave>>1, wn=wave&1).
// LDS [row][slot(=ks^ (row&7))][8] bf16: conflict-free write+read.
__global__ __launch_bounds__(512, 2) void fc1_k(
    const float* __restrict__ inputs, const float* __restrict__ W1,
    const float* __restrict__ b1, __bf16* __restrict__ x1) {
  const int wg = xcd_swz(blockIdx.x, gridDim.x);
  const int a  = wg >> 3;
  const int n0 = (wg & 7) * 64;

  __shared__ __attribute__((aligned(16))) __bf16 lA[2][256][8][8];
  __shared__ __attribute__((aligned(16))) __bf16 lB[2][64][8][8];

  const int tid = threadIdx.x;
  const int lane = tid & 63;
  const int wave = tid >> 6;
  const int wm = wave >> 1, wn = wave & 1;
  const int lr = lane & 15, lk = lane >> 4;

  // staging: A = 256x64 fp32 -> 4 chunks/thread; B = 64x64 fp32 -> 1 chunk
  int arow[4], aks[4]; size_t aoff[4];
#pragma unroll
  for (int c = 0; c < 4; ++c) {
    const int idx = c * 512 + tid;
    arow[c] = idx >> 3; aks[c] = idx & 7;
    aoff[c] = ((size_t)arow[c] * NAGENT + a) * KC + aks[c] * 8;
  }
  const int brow = tid >> 3, bks = tid & 7;
  const size_t boff = ((size_t)a * 512 + n0 + brow) * KC + bks * 8;

  bf16x8 sA[4], sB;
  auto loadT = [&](int t) {
    const int kb = t * 64;
#pragma unroll
    for (int c = 0; c < 4; ++c) sA[c] = cvt8(inputs + aoff[c] + kb);
    sB = cvt8(W1 + boff + kb);
  };
  auto writeT = [&](int buf) {
#pragma unroll
    for (int c = 0; c < 4; ++c)
      *(bf16x8*)(&lA[buf][arow[c]][aks[c] ^ (arow[c] & 7)][0]) = sA[c];
    *(bf16x8*)(&lB[buf][brow][bks ^ (brow & 7)][0]) = sB;
  };

  f32x4 acc[4][2] = {};
  auto computeT = [&](int buf) {
#pragma unroll
    for (int s = 0; s < 2; ++s) {
      const int ks = s * 4 + lk;
      bf16x8 af[4];
#pragma unroll
      for (int i = 0; i < 4; ++i) {
        const int row = wm * 64 + i * 16 + lr;
        af[i] = *(const bf16x8*)(&lA[buf][row][ks ^ (row & 7)][0]);
      }
#pragma unroll
      for (int cb = 0; cb < 2; ++cb) {
        const int br = wn * 32 + cb * 16 + lr;
        bf16x8 bv = *(const bf16x8*)(&lB[buf][br][ks ^ (br & 7)][0]);
#pragma unroll
        for (int i = 0; i < 4; ++i)
          acc[i][cb] = __builtin_amdgcn_mfma_f32_16x16x32_bf16(af[i], bv, acc[i][cb], 0, 0, 0);
      }
    }
  };

  loadT(0); writeT(0);
  int cur = 0;
#pragma unroll 1
  for (int t = 0; t < 8; ++t) {
    __syncthreads();
    if (t < 7) loadT(t + 1);
    computeT(cur);
    if (t < 7) { writeT(cur ^ 1); cur ^= 1; }
  }

#pragma unroll
  for (int cb = 0; cb < 2; ++cb) {
    const int col = n0 + wn * 32 + cb * 16 + lr;
    const float bias = b1[(size_t)a * 512 + col];
#pragma unroll
    for (int i = 0; i < 4; ++i) {
      const int r0 = wm * 64 + i * 16 + lk * 4;
#pragma unroll
      for (int e = 0; e < 4; ++e) {
        const float v = fmaxf(acc[i][cb][e] + bias, 0.f);
        x1[((size_t)(r0 + e) * NAGENT + a) * KC + col] = (__bf16)v;
      }
    }
  }
}

// ---------------------------------------------------------------------------
// Fused GRU: BM=256 rows x (3 gates x 64 cols), K = 512(x1@Wih) + 512(hid@Whh).
// accR/accZ fuse both K-phases; n-gate kept split (accXN, accHN) for the
// r*gh_n structure. Grid 256 = 32 agents x 8 col-tiles. 512 threads.
__global__ __launch_bounds__(512, 2) void gru_k(
    const __bf16* __restrict__ x1, const float* __restrict__ hidden,
    const float* __restrict__ Wih, const float* __restrict__ bih,
    const float* __restrict__ Whh, const float* __restrict__ bhh,
    float* __restrict__ hout, __bf16* __restrict__ hbf) {
  const int wg = xcd_swz(blockIdx.x, gridDim.x);
  const int a  = wg >> 3;
  const int n0 = (wg & 7) * 64;

  __shared__ __attribute__((aligned(16))) __bf16 lA[2][256][8][8];  // 64 KiB
  __shared__ __attribute__((aligned(16))) __bf16 lB[2][192][8][8];  // 48 KiB

  const int tid = threadIdx.x;
  const int lane = tid & 63;
  const int wave = tid >> 6;
  const int wm = wave >> 1, wn = wave & 1;
  const int lr = lane & 15, lk = lane >> 4;

  int arow[4], aks[4]; size_t aoff[4];
#pragma unroll
  for (int c = 0; c < 4; ++c) {
    const int idx = c * 512 + tid;
    arow[c] = idx >> 3; aks[c] = idx & 7;
    aoff[c] = ((size_t)arow[c] * NAGENT + a) * KC + aks[c] * 8;
  }
  int brow[3], bks[3]; size_t boff[3];
#pragma unroll
  for (int c = 0; c < 3; ++c) {
    const int idx = c * 512 + tid;
    brow[c] = idx >> 3; bks[c] = idx & 7;
    const int g = brow[c] >> 6, col = brow[c] & 63;
    boff[c] = ((size_t)a * 1536 + g * 512 + n0 + col) * KC + bks[c] * 8;
  }

  bf16x8 sA[4], sB[3];
  auto loadT = [&](int t) {
    if (t < 8) {
      const int kb = t * 64;
#pragma unroll
      for (int c = 0; c < 4; ++c) sA[c] = *(const bf16x8*)(x1 + aoff[c] + kb);
#pragma unroll
      for (int c = 0; c < 3; ++c) sB[c] = cvt8(Wih + boff[c] + kb);
    } else {
      const int kb = (t - 8) * 64;
#pragma unroll
      for (int c = 0; c < 4; ++c) sA[c] = cvt8(hidden + aoff[c] + kb);
#pragma unroll
      for (int c = 0; c < 3; ++c) sB[c] = cvt8(Whh + boff[c] + kb);
    }
  };
  auto writeT = [&](int buf) {
#pragma unroll
    for (int c = 0; c < 4; ++c)
      *(bf16x8*)(&lA[buf][arow[c]][aks[c] ^ (arow[c] & 7)][0]) = sA[c];
#pragma unroll
    for (int c = 0; c < 3; ++c)
      *(bf16x8*)(&lB[buf][brow[c]][bks[c] ^ (brow[c] & 7)][0]) = sB[c];
  };

  f32x4 accR[4][2] = {}, accZ[4][2] = {}, accXN[4][2] = {}, accHN[4][2] = {};
  auto computeT = [&](int buf, f32x4 (&accN)[4][2]) {
#pragma unroll
    for (int s = 0; s < 2; ++s) {
      const int ks = s * 4 + lk;
      bf16x8 af[4];
#pragma unroll
      for (int i = 0; i < 4; ++i) {
        const int row = wm * 64 + i * 16 + lr;
        af[i] = *(const bf16x8*)(&lA[buf][row][ks ^ (row & 7)][0]);
      }
#pragma unroll
      for (int cb = 0; cb < 2; ++cb) {
        const int c0 = wn * 32 + cb * 16 + lr;
        bf16x8 bR = *(const bf16x8*)(&lB[buf][c0][ks ^ (c0 & 7)][0]);
        bf16x8 bZ = *(const bf16x8*)(&lB[buf][64 + c0][ks ^ (c0 & 7)][0]);
        bf16x8 bN = *(const bf16x8*)(&lB[buf][128 + c0][ks ^ (c0 & 7)][0]);
#pragma unroll
        for (int i = 0; i < 4; ++i) {
          accR[i][cb] = __builtin_amdgcn_mfma_f32_16x16x32_bf16(af[i], bR, accR[i][cb], 0, 0, 0);
          accZ[i][cb] = __builtin_amdgcn_mfma_f32_16x16x32_bf16(af[i], bZ, accZ[i][cb], 0, 0, 0);
          accN[i][cb] = __builtin_amdgcn_mfma_f32_16x16x32_bf16(af[i], bN, accN[i][cb], 0, 0, 0);
        }
      }
    }
  };

  loadT(0); writeT(0);
  int cur = 0;
  // phase 0: x1 @ W_ih (t 0..7), n-gate -> accXN
#pragma unroll 1
  for (int t = 0; t < 8; ++t) {
    __syncthreads();
    loadT(t + 1);  // t=7 prefetches the hidden/Whh phase
    computeT(cur, accXN);
    writeT(cur ^ 1); cur ^= 1;
  }
  // phase 1: hidden @ W_hh (t 8..15), n-gate -> accHN
#pragma unroll 1
  for (int t = 8; t < 16; ++t) {
    __syncthreads();
    if (t < 15) loadT(t + 1);
    computeT(cur, accHN);
    if (t < 15) { writeT(cur ^ 1); cur ^= 1; }
  }

  // epilogue: full GRU gate math in-register; hidden re-read is L2-hot.
#pragma unroll
  for (int cb = 0; cb < 2; ++cb) {
    const int col = n0 + wn * 32 + cb * 16 + lr;
    const size_t ab = (size_t)a * 1536 + col;
    const float br_ = bih[ab] + bhh[ab];
    const float bz_ = bih[ab + 512] + bhh[ab + 512];
    const float bxn = bih[ab + 1024];
    const float bhn = bhh[ab + 1024];
#pragma unroll
    for (int i = 0; i < 4; ++i) {
      const int r0 = wm * 64 + i * 16 + lk * 4;
#pragma unroll
      for (int e = 0; e < 4; ++e) {
        const size_t o = ((size_t)(r0 + e) * NAGENT + a) * KC + col;
        const float hprev = hidden[o];
        const float r = sigmoid_f(accR[i][cb][e] + br_);
        const float z = sigmoid_f(accZ[i][cb][e] + bz_);
        const float n = tanh_f((accXN[i][cb][e] + bxn) + r * (accHN[i][cb][e] + bhn));
        const float h = (1.f - z) * n + z * hprev;
        hout[o] = h;
        hbf[o] = (__bf16)h;
      }
    }
  }
}

// ---------------------------------------------------------------------------
// fc2 (tiny): 64x64 tile GEMM, proven in round 2. Grid 128 = 32 agents x 4 M.
template <bool ABF16, int ACT, bool OBF16>
__global__ __launch_bounds__(256) void gemm64(
    const void* __restrict__ Ap, const float* __restrict__ Wp,
    const float* __restrict__ bp, void* __restrict__ Op, const int N) {
  constexpr int BM = 64, MT = 4;
  const int NT = N >> 6;
  const int wg = xcd_swz(blockIdx.x, gridDim.x);
  const int a  = wg / (MT * NT);
  const int rem = wg % (MT * NT);
  const int n0 = (rem / MT) * 64;
  const int b0 = (rem % MT) * BM;

  __shared__ __attribute__((aligned(16))) __bf16 lA[2][4][64][8];
  __shared__ __attribute__((aligned(16))) __bf16 lB[2][4][64][8];

  const int tid = threadIdx.x;
  const int lane = tid & 63;
  const int wn = tid >> 6;
  const int lr = lane & 15, lk = lane >> 4;

  const int ar = tid >> 2, aks = tid & 3;
  const size_t aoff = ((size_t)(b0 + ar) * NAGENT + a) * KC + aks * 8;
  const size_t boff = ((size_t)a * N + n0 + ar) * KC + aks * 8;

  const float*  Af = (const float*)Ap;
  const __bf16* Ab = (const __bf16*)Ap;

  bf16x8 sA, sB;
  auto loadT = [&](int t) {
    if constexpr (ABF16) sA = *(const bf16x8*)(Ab + aoff + t * 32);
    else                 sA = cvt8(Af + aoff + t * 32);
    sB = cvt8(Wp + boff + t * 32);
  };
  auto writeT = [&](int buf) {
    *(bf16x8*)(&lA[buf][aks][ar][0]) = sA;
    *(bf16x8*)(&lB[buf][aks][ar][0]) = sB;
  };

  f32x4 acc[4] = {};
  auto computeT = [&](int buf) {
    bf16x8 bv = *(const bf16x8*)(&lB[buf][lk][wn * 16 + lr][0]);
#pragma unroll
    for (int i = 0; i < 4; ++i) {
      bf16x8 af = *(const bf16x8*)(&lA[buf][lk][i * 16 + lr][0]);
      acc[i] = __builtin_amdgcn_mfma_f32_16x16x32_bf16(af, bv, acc[i], 0, 0, 0);
    }
  };

  loadT(0); writeT(0);
  int cur = 0;
#pragma unroll 1
  for (int t = 0; t < KC / 32; ++t) {
    __syncthreads();
    if (t + 1 < KC / 32) loadT(t + 1);
    computeT(cur);
    if (t + 1 < KC / 32) { writeT(cur ^ 1); cur ^= 1; }
  }

  const int col = n0 + wn * 16 + lr;
  const float bias = bp[(size_t)a * N + col];
#pragma unroll
  for (int i = 0; i < 4; ++i) {
    const int r0 = b0 + i * 16 + lk * 4;
#pragma unroll
    for (int e = 0; e < 4; ++e) {
      float v = acc[i][e] + bias;
      if (ACT == 1) v = fmaxf(v, 0.f);
      const size_t o = ((size_t)(r0 + e) * NAGENT + a) * N + col;
      if constexpr (OBF16) ((__bf16*)Op)[o] = (__bf16)v;
      else                 ((float*)Op)[o]  = v;
    }
  }
}

extern "C" void kernel_launch(void* const* d_in, const int* in_sizes, int n_in,
                              void* d_out, int out_size, void* d_ws, size_t ws_size,
                              hipStream_t stream) {
  const float* inputs = (const float*)d_in[0];
  const float* hidden = (const float*)d_in[1];
  const float* W1   = (const float*)d_in[2];
  const float* b1   = (const float*)d_in[3];
  const float* W_ih = (const float*)d_in[4];
  const float* b_ih = (const float*)d_in[5];
  const float* W_hh = (const float*)d_in[6];
  const float* b_hh = (const float*)d_in[7];
  const float* W2   = (const float*)d_in[8];
  const float* b2   = (const float*)d_in[9];

  float* out_q = (float*)d_out;
  float* out_h = out_q + (size_t)8192 * 64;

  char* ws = (char*)d_ws;
  __bf16* x1  = (__bf16*)(ws);                      // 8 MiB [8192,512] bf16
  __bf16* hbf = (__bf16*)(ws + ((size_t)8 << 20));  // 8 MiB [8192,512] bf16

  fc1_k<<<256, 512, 0, stream>>>(inputs, W1, b1, x1);
  gru_k<<<256, 512, 0, stream>>>(x1, hidden, W_ih, b_ih, W_hh, b_hh, out_h, hbf);
  gemm64<true, 0, false><<<128, 256, 0, stream>>>(hbf, W2, b2, out_q, 64);
}